// Round 10
// baseline (26313.535 us; speedup 1.0000x reference)
//
#include <hip/hip_runtime.h>
#include <math.h>

#define NB 32
#define NN 32
#define NSTEPS 600
#define NT1 601
#define NSI 10
#define NH 75
#define NU 80      // padded u (8 groups x 10)
#define NKB 20     // padded k-blocks of 4 (k padded 75 -> 80)
#define KBG 5      // k-blocks per lane-group (4 groups)

#define ICM2IFS 2.99792458e-05
#define KBOLTZ 0.6950389f
#define TWO_PI 6.283185307179586476925286766559

__device__ __forceinline__ float elu1(float x) { return x > 0.f ? x : (__expf(x) - 1.f); }

// ---------------------------------------------------------------------------
// Phase A: batched 32x32 symmetric eigensolver (parallel cyclic Jacobi).
// A/rotations in FP64 (angles gap-sensitive); V accumulated in FP32 (errors
// ~1e-7/apply, no amplification; final vectors stored fp32 anyway). V in fp32
// halves LDS -> more blocks/CU.
// ---------------------------------------------------------------------------
__global__ __launch_bounds__(64) void eigh_kernel(const float* __restrict__ Hf,
                                                  float* __restrict__ E_all,
                                                  float* __restrict__ CT_all)
{
    __shared__ double A[NN][NN + 1];
    __shared__ float  V[NN][NN + 1];
    __shared__ double csC[16], csS[16];
    __shared__ int   prC[16], qrC[16];
    __shared__ double redv;
    __shared__ int   rankl[NN];

    const int idx = blockIdx.x;      // b*601 + t
    const int tid = threadIdx.x;
    const float* Hp = Hf + (size_t)idx * (NN * NN);

    for (int e = tid; e < NN * NN; e += 64) {
        A[e >> 5][e & 31] = (double)Hp[e];
        V[e >> 5][e & 31] = ((e >> 5) == (e & 31)) ? 1.f : 0.f;
    }
    __syncthreads();

    double part = 0.0;
    for (int e = tid; e < NN * NN; e += 64) { double v = A[e >> 5][e & 31]; part += v * v; }
    #pragma unroll
    for (int off = 32; off > 0; off >>= 1) part += __shfl_down(part, off);
    if (tid == 0) redv = part;
    __syncthreads();
    const double tol2 = 1e-20 * redv;

    for (int sweep = 0; sweep < 10; ++sweep) {
        for (int r = 0; r < NN - 1; ++r) {
            if (tid < 16) {
                int m = tid, p, q;
                if (m == 0) { p = 0; q = 1 + (r % 31); }
                else { p = 1 + ((m + r) % 31); q = 1 + ((31 - m + r) % 31); }
                double apq = A[p][q];
                double c = 1.0, sn = 0.0;
                if (apq != 0.0) {
                    double theta = 0.5 * (A[q][q] - A[p][p]) / apq;
                    double tt = 1.0 / (fabs(theta) + sqrt(theta * theta + 1.0));
                    if (theta < 0.0) tt = -tt;
                    c = 1.0 / sqrt(tt * tt + 1.0);
                    sn = tt * c;
                }
                csC[m] = c; csS[m] = sn; prC[m] = p; qrC[m] = q;
            }
            __syncthreads();
            #pragma unroll
            for (int it = 0; it < 8; ++it) {          // rows: A <- J^T A
                int task = tid + it * 64;
                int m = task >> 5, jc = task & 31;
                int p = prC[m], q = qrC[m];
                double c = csC[m], sn = csS[m];
                double ap = A[p][jc], aq = A[q][jc];
                A[p][jc] = c * ap - sn * aq;
                A[q][jc] = sn * ap + c * aq;
            }
            __syncthreads();
            #pragma unroll
            for (int it = 0; it < 16; ++it) {         // cols: A <- A J (f64), V <- V J (f32)
                int task = tid + it * 64;
                int m = (task >> 5) & 15, ir = task & 31;
                int p = prC[m], q = qrC[m];
                if (task < 512) {
                    double c = csC[m], sn = csS[m];
                    double aip = A[ir][p], aiq = A[ir][q];
                    A[ir][p] = c * aip - sn * aiq;
                    A[ir][q] = sn * aip + c * aiq;
                } else {
                    float cf = (float)csC[m], sf = (float)csS[m];
                    float vip = V[ir][p], viq = V[ir][q];
                    V[ir][p] = cf * vip - sf * viq;
                    V[ir][q] = sf * vip + cf * viq;
                }
            }
            __syncthreads();
        }
        if (sweep >= 3) {
            double o = 0.0;
            for (int e = tid; e < NN * NN; e += 64) {
                int i2 = e >> 5, j2 = e & 31;
                double v = A[i2][j2];
                o += (i2 != j2) ? v * v : 0.0;
            }
            #pragma unroll
            for (int off = 32; off > 0; off >>= 1) o += __shfl_down(o, off);
            if (tid == 0) redv = o;
            __syncthreads();
            if (redv <= tol2) break;
        }
    }
    __syncthreads();

    if (tid < NN) {
        double ei = A[tid][tid];
        int rk = 0;
        for (int j2 = 0; j2 < NN; ++j2) {
            double ej = A[j2][j2];
            rk += (ej < ei || (ej == ei && j2 < tid)) ? 1 : 0;
        }
        rankl[tid] = rk;
        E_all[(size_t)idx * NN + rk] = (float)ei;
    }
    __syncthreads();
    float* ct = CT_all + (size_t)idx * NN * NN;
    for (int e = tid; e < NN * NN; e += 64) {
        int col = e >> 5, m2 = e & 31;
        ct[(size_t)rankl[col] * NN + m2] = V[m2][col];
    }
}

// ---------------------------------------------------------------------------
// Phase A2: kk[b,s,j] = argmax_i S[b,s,i,j]^2 (first index on ties)
// ---------------------------------------------------------------------------
__global__ __launch_bounds__(256) void kk_kernel(const float* __restrict__ CT_all,
                                                 int* __restrict__ kk_all)
{
    __shared__ float Ct[NN][NN + 1], Cp[NN][NN + 1], S[NN][NN + 1];
    const int blk = blockIdx.x;                // b*600 + (s-1)
    const int b = blk / NSTEPS, s = blk % NSTEPS + 1;
    const int tid = threadIdx.x;
    const float* ctg = CT_all + ((size_t)b * NT1 + s) * (NN * NN);
    const float* cpg = CT_all + ((size_t)b * NT1 + s - 1) * (NN * NN);
    for (int e = tid; e < NN * NN; e += 256) {
        Ct[e >> 5][e & 31] = ctg[e];
        Cp[e >> 5][e & 31] = cpg[e];
    }
    __syncthreads();
    for (int e = tid; e < NN * NN; e += 256) {
        int i = e >> 5, j = e & 31;
        float acc = 0.f;
        for (int m = 0; m < NN; ++m) acc += Ct[i][m] * Cp[j][m];
        S[i][j] = acc;
    }
    __syncthreads();
    if (tid < NN) {
        const int j = tid;
        float best = -1.f; int bi = 0;
        for (int i = 0; i < NN; ++i) {
            float v = S[i][j]; v *= v;
            if (v > best) { best = v; bi = i; }
        }
        kk_all[(size_t)blk * NN + j] = bi;
    }
}

// ---------------------------------------------------------------------------
// Pack weights for split-k GEMM: Wp[ug 8][kb 20][kp 4][12] (10 u + 2 pad,
// each kp-row 16B-aligned; zero for u>=75 or k>=75).
// L1W4/L1B4 float4; bpad = b2[80] | b3[80] | W4[80].
// ---------------------------------------------------------------------------
__global__ void wtrans_kernel(const float* __restrict__ W1, const float* __restrict__ b1,
                              const float* __restrict__ W2, const float* __restrict__ W3,
                              const float* __restrict__ b2, const float* __restrict__ b3,
                              const float* __restrict__ W4,
                              float* __restrict__ W2p, float* __restrict__ W3p,
                              float4* __restrict__ L1W4, float4* __restrict__ L1B4,
                              float* __restrict__ bpad)
{
    const int tid = threadIdx.x;
    const int tot = 8 * NKB * 4 * 12;          // 7680
    for (int e = tid; e < tot; e += 256) {
        int ug = e / (NKB * 4 * 12);
        int kb = (e / (4 * 12)) % NKB;
        int kp = (e / 12) & 3;
        int uu = e % 12;
        int u = ug * 10 + uu;
        int k = kb * 4 + kp;
        float v2 = 0.f, v3 = 0.f;
        if (uu < 10 && u < NH && k < NH) {
            v2 = W2[u * NH + k];
            v3 = W3[u * NH + k];
        }
        W2p[e] = v2; W3p[e] = v3;
    }
    if (tid < NU) {
        if (tid < NH) {
            const float* w = W1 + tid * 8;
            L1W4[tid] = make_float4(w[0], w[1], w[2], w[7]);
            L1B4[tid] = make_float4(w[3], w[4], w[5], b1[tid]);
            bpad[tid]          = b2[tid];
            bpad[NU + tid]     = b3[tid];
            bpad[2 * NU + tid] = W4[tid];
        } else {
            L1W4[tid] = make_float4(0.f, 0.f, 0.f, 0.f);
            L1B4[tid] = make_float4(0.f, 0.f, 0.f, 0.f);
            bpad[tid] = 0.f; bpad[NU + tid] = 0.f; bpad[2 * NU + tid] = 0.f;
        }
    }
}

// ---------------------------------------------------------------------------
// Phase B: ONE persistent kernel, 256 blocks x 512 thr.
// Wave = ug (10 u). Lane = (g = lane>>4 k-group, rl = lane&15 -> rows rl*8..+7).
// Group g handles kb in {5g..5g+4}: weight reads are 4-address ds_read_b128
// (parity-paired -> 2-way = free), h reads per-lane-distinct b128 (full BW).
// k-partials summed via shfl_xor(16/32) butterfly. 60+40 LDS instr/wave/layer
// vs R9's 228 broadcasts. Everything else (barrier, fp64 prologue, prefetch)
// is the R6/R9-proven structure.
// ---------------------------------------------------------------------------
__global__ __launch_bounds__(512, 2) void persist_kernel(
    const float* __restrict__ E_all, const float* __restrict__ CT_all,
    const int* __restrict__ kk_all, const float* __restrict__ psi0,
    const float* __restrict__ Tarr, const float* __restrict__ ErA,
    const float* __restrict__ ctA, const float* __restrict__ dtA,
    const float* __restrict__ W2p, const float* __restrict__ W3p,
    const float4* __restrict__ L1W4g, const float4* __restrict__ L1B4g,
    const float* __restrict__ bpad, const float* __restrict__ b4v,
    float* __restrict__ S2_g, unsigned int* __restrict__ cnt,
    float* __restrict__ out)
{
    extern __shared__ __align__(16) float dyn[];
    float* W2s = dyn;                           // 7680
    float* W3s = W2s + 8 * NKB * 48;            // 7680
    float4* L1Wl = (float4*)(W3s + 8 * NKB * 48);    // 80 f4
    float4* L1Bl = L1Wl + NU;                   // 80 f4
    float* cst  = (float*)(L1Bl + NU);          // 80
    float* b2l  = cst + NU;                     // 80
    float* b3l  = b2l + NU;                     // 80
    float* W4l  = b3l + NU;                     // 80
    float* hbuf = W4l + NU;                     // 80*128 = 10240

    __shared__ float CpN[2][NN][NN + 1];
    __shared__ float S2l[NN][NN + 1];
    __shared__ float4 featS[128];               // {DE, ratio, Sv, ex} per row
    __shared__ float a4b[8][128];
    __shared__ float EL[2][NN];
    __shared__ int   kkL[2][NN];
    __shared__ double phre[NN], phim[NN], redl[NN];
    __shared__ float phi2l[NN];

    const int tid  = threadIdx.x;
    const int b    = blockIdx.x & 31;           // siblings: b, 32+b, ..., 224+b
    const int iblk = blockIdx.x >> 5;
    const int i0   = iblk * 4;
    const int ug   = tid >> 6;                  // wave id = u-group
    const int lane = tid & 63;
    const int g    = lane >> 4;                 // k-group
    const int rl   = lane & 15;                 // row slice: rows rl*8 .. rl*8+7
    const int U    = ug * 10;

    const float kbt = KBOLTZ * Tarr[b];
    const float er  = ErA[b];
    const float cti = ctA[b];
    const double dtb = (double)dtA[b];
    const float b4s = b4v[0];

    // ---- stage loop-invariant weights into LDS (once) ----
    for (int e = tid; e < 8 * NKB * 48; e += 512) { W2s[e] = W2p[e]; W3s[e] = W3p[e]; }
    if (tid < NU) {
        L1Wl[tid] = L1W4g[tid];
        L1Bl[tid] = L1B4g[tid];
        b2l[tid] = bpad[tid];
        b3l[tid] = bpad[NU + tid];
        W4l[tid] = bpad[2 * NU + tid];
    }
    __syncthreads();
    if (tid < NU) {     // per-b constant part of layer-1 preactivation
        float4 lb = L1Bl[tid];
        cst[tid] = lb.w + lb.x * kbt + lb.y * er + lb.z * cti;
    }

    // ---- prime: C_0, C_1, E[0], E[1], kk[0]; init phiB ----
    {
        const float* c0g = CT_all + (size_t)b * NT1 * NN * NN;
        const float* c1g = c0g + NN * NN;
        for (int e = tid; e < NN * NN; e += 512) {
            CpN[0][e >> 5][e & 31] = c0g[e];
            CpN[1][e >> 5][e & 31] = c1g[e];
        }
        if (tid < NN) {
            EL[0][tid] = E_all[((size_t)b * NT1 + 0) * NN + tid];
            EL[1][tid] = E_all[((size_t)b * NT1 + 1) * NN + tid];
            kkL[1][tid] = kk_all[(size_t)b * NSTEPS * NN + tid];
        }
        __syncthreads();
        if (tid < NN) {
            const int i = tid;
            double acc = 0.0;
            for (int j = 0; j < NN; ++j) acc += (double)CpN[0][i][j] * (double)psi0[b * NN + j];
            phre[i] = acc; phim[i] = 0.0;
            phi2l[i] = (float)(acc * acc);
            if (iblk == 0) {
                float p0 = psi0[b * NN + i];
                out[((size_t)b * 61) * NN + i] = p0 * p0;
            }
        }
    }

    const float4* hb4 = (const float4*)hbuf;

    for (int t = 1; t <= NSTEPS; ++t) {
        __syncthreads();
        const int cur = t & 1;

        // ---- features (one thread per row) ----
        if (tid < 128) {
            const int r = tid;
            const int i = i0 + (r >> 5);
            const int j = r & 31;
            float Sv = 0.f;
            for (int m = 0; m < NN; ++m) Sv += CpN[cur][i][m] * CpN[1 - cur][j][m];
            const int kj = kkL[cur][j];
            const float DE = (i == kj) ? 0.f : (EL[cur][i] - EL[1 - cur][j]);
            const float p_i = phi2l[i], p_j = phi2l[j];
            const float ratio = (p_j > 0.01f * p_i) ? (p_i / p_j) : 100.f;
            const float ex = __expf(DE / kbt);
            featS[r] = make_float4(DE, ratio, Sv, ex);
        }
        __syncthreads();

        // ---- issue prefetch loads for step t+1 (retire during MLP) ----
        float2 cpre = make_float2(0.f, 0.f);
        float  epre = 0.f;
        int    kpre = 0;
        if (t < NSTEPS) {
            const float* c1g = CT_all + ((size_t)b * NT1 + t + 1) * (NN * NN);
            cpre = ((const float2*)c1g)[tid];
            if (tid < NN) epre = E_all[((size_t)b * NT1 + t + 1) * NN + tid];
            else if (tid < 2 * NN) kpre = kk_all[((size_t)b * NSTEPS + t) * NN + (tid - NN)];
        }

        // ---- layer 1 (features -> h1): wave ug writes its 10 u x 128 r ----
        {
            float4 f0 = featS[2 * lane], f1 = featS[2 * lane + 1];
            #pragma unroll
            for (int u = 0; u < 10; ++u) {
                float4 wv = L1Wl[U + u];
                float c = cst[U + u];
                float2 hv;
                hv.x = elu1(c + wv.x * f0.x + wv.y * f0.y + wv.z * f0.z + wv.w * f0.w);
                hv.y = elu1(c + wv.x * f1.x + wv.y * f1.y + wv.z * f1.z + wv.w * f1.w);
                *(float2*)(hbuf + (U + u) * 128 + 2 * lane) = hv;
            }
        }
        __syncthreads();

        float4 acc[10][2];
        // ================= layer 2 (split-k) =================
        #pragma unroll
        for (int u = 0; u < 10; ++u) {
            float bb = b2l[U + u];
            acc[u][0] = make_float4(bb, bb, bb, bb);
            acc[u][1] = make_float4(0.f, 0.f, 0.f, 0.f);   // only group partials; bias once
        }
        // bias counted 4x after butterfly if in all groups -> put bias only in g==0
        if (g != 0) {
            #pragma unroll
            for (int u = 0; u < 10; ++u) acc[u][0] = make_float4(0.f, 0.f, 0.f, 0.f);
        }
        {
            const float4* Wug = (const float4*)(W2s + ug * (NKB * 48));
            for (int it = 0; it < KBG; ++it) {
                const int kb = g * KBG + it;
                float4 wv[12], hv[4][2];
                #pragma unroll
                for (int m = 0; m < 12; ++m) wv[m] = Wug[kb * 12 + m];
                #pragma unroll
                for (int kp = 0; kp < 4; ++kp) {
                    hv[kp][0] = hb4[(kb * 4 + kp) * 32 + rl * 2];
                    hv[kp][1] = hb4[(kb * 4 + kp) * 32 + rl * 2 + 1];
                }
                #pragma unroll
                for (int kp = 0; kp < 4; ++kp) {
                    const float* wf = (const float*)&wv[kp * 3];
                    #pragma unroll
                    for (int u = 0; u < 10; ++u) {
                        float wS = wf[u];
                        acc[u][0].x += wS * hv[kp][0].x; acc[u][0].y += wS * hv[kp][0].y;
                        acc[u][0].z += wS * hv[kp][0].z; acc[u][0].w += wS * hv[kp][0].w;
                        acc[u][1].x += wS * hv[kp][1].x; acc[u][1].y += wS * hv[kp][1].y;
                        acc[u][1].z += wS * hv[kp][1].z; acc[u][1].w += wS * hv[kp][1].w;
                    }
                }
            }
        }
        {   // butterfly over k-groups
            float* af = (float*)acc;
            #pragma unroll
            for (int q = 0; q < 80; ++q) {
                af[q] += __shfl_xor(af[q], 16);
                af[q] += __shfl_xor(af[q], 32);
            }
        }
        __syncthreads();    // all reads of h1 done before overwriting hbuf
        if (g == 0) {
            #pragma unroll
            for (int u = 0; u < 10; ++u) {
                float4 h0, h1;
                h0.x = elu1(acc[u][0].x); h0.y = elu1(acc[u][0].y);
                h0.z = elu1(acc[u][0].z); h0.w = elu1(acc[u][0].w);
                h1.x = elu1(acc[u][1].x); h1.y = elu1(acc[u][1].y);
                h1.z = elu1(acc[u][1].z); h1.w = elu1(acc[u][1].w);
                *(float4*)(hbuf + (U + u) * 128 + rl * 8)     = h0;
                *(float4*)(hbuf + (U + u) * 128 + rl * 8 + 4) = h1;
            }
        }
        __syncthreads();

        // ================= layer 3 (split-k, h3 in registers) =================
        #pragma unroll
        for (int u = 0; u < 10; ++u) {
            float bb = (g == 0) ? b3l[U + u] : 0.f;
            acc[u][0] = make_float4(bb, bb, bb, bb);
            acc[u][1] = make_float4(bb, bb, bb, bb);
            acc[u][1].x = bb; // (same as above; kept simple)
        }
        {
            const float4* Wug = (const float4*)(W3s + ug * (NKB * 48));
            for (int it = 0; it < KBG; ++it) {
                const int kb = g * KBG + it;
                float4 wv[12], hv[4][2];
                #pragma unroll
                for (int m = 0; m < 12; ++m) wv[m] = Wug[kb * 12 + m];
                #pragma unroll
                for (int kp = 0; kp < 4; ++kp) {
                    hv[kp][0] = hb4[(kb * 4 + kp) * 32 + rl * 2];
                    hv[kp][1] = hb4[(kb * 4 + kp) * 32 + rl * 2 + 1];
                }
                #pragma unroll
                for (int kp = 0; kp < 4; ++kp) {
                    const float* wf = (const float*)&wv[kp * 3];
                    #pragma unroll
                    for (int u = 0; u < 10; ++u) {
                        float wS = wf[u];
                        acc[u][0].x += wS * hv[kp][0].x; acc[u][0].y += wS * hv[kp][0].y;
                        acc[u][0].z += wS * hv[kp][0].z; acc[u][0].w += wS * hv[kp][0].w;
                        acc[u][1].x += wS * hv[kp][1].x; acc[u][1].y += wS * hv[kp][1].y;
                        acc[u][1].z += wS * hv[kp][1].z; acc[u][1].w += wS * hv[kp][1].w;
                    }
                }
            }
        }
        {   // butterfly over k-groups
            float* af = (float*)acc;
            #pragma unroll
            for (int q = 0; q < 80; ++q) {
                af[q] += __shfl_xor(af[q], 16);
                af[q] += __shfl_xor(af[q], 32);
            }
        }
        // ---- layer 4 partials ----
        if (g == 0) {
            float4 p0 = make_float4(0.f, 0.f, 0.f, 0.f);
            float4 p1 = make_float4(0.f, 0.f, 0.f, 0.f);
            #pragma unroll
            for (int u = 0; u < 10; ++u) {
                float w4 = W4l[U + u];
                p0.x += w4 * elu1(acc[u][0].x); p0.y += w4 * elu1(acc[u][0].y);
                p0.z += w4 * elu1(acc[u][0].z); p0.w += w4 * elu1(acc[u][0].w);
                p1.x += w4 * elu1(acc[u][1].x); p1.y += w4 * elu1(acc[u][1].y);
                p1.z += w4 * elu1(acc[u][1].z); p1.w += w4 * elu1(acc[u][1].w);
            }
            *(float4*)&a4b[ug][rl * 8]     = p0;
            *(float4*)&a4b[ug][rl * 8 + 4] = p1;
        }
        __syncthreads();
        if (tid < 128) {
            const int r = tid;
            float a4 = b4s;
            #pragma unroll
            for (int gg = 0; gg < 8; ++gg) a4 += a4b[gg][r];
            const float corr = elu1(a4) + 1.f;
            const float Sv = featS[r].z;
            const int i = i0 + (r >> 5);
            const int j = r & 31;
            S2_g[(((size_t)cur * NB + b) * NN + i) * NN + j] = Sv * corr;
            __threadfence();                    // make S2 agent-visible
        }
        __syncthreads();

        // ---- sibling barrier (8 blocks of this b), per-step counter ----
        if (tid == 0) {
            unsigned int* c = cnt + (size_t)b * NSTEPS + (t - 1);
            __hip_atomic_fetch_add(c, 1u, __ATOMIC_RELEASE, __HIP_MEMORY_SCOPE_AGENT);
            while (__hip_atomic_load(c, __ATOMIC_ACQUIRE, __HIP_MEMORY_SCOPE_AGENT) < 8u)
                __builtin_amdgcn_s_sleep(1);
        }
        __syncthreads();

        // ---- complete step t (replicated per block, fp64) ----
        {
            const float* s2src = S2_g + ((size_t)cur * NB + b) * (NN * NN);
            for (int e = tid; e < NN * NN; e += 512) S2l[e >> 5][e & 31] = s2src[e];
        }
        __syncthreads();
        if (tid < NN) {                 // column correction (kk = kk_all[t-1])
            const int jj = tid;
            const int kj2 = kkL[cur][jj];
            double cd = 0.0;
            for (int i2 = 0; i2 < NN; ++i2) {
                double v = (double)S2l[i2][jj];
                cd += (i2 == kj2) ? 0.0 : v * v;
            }
            double skk = (double)S2l[kj2][jj];
            double nrm = fabs(skk); nrm = (nrm > 0.0) ? nrm : 1.0;
            double rem = 1.0 - cd;
            S2l[kj2][jj] = (float)((rem > 0.0) ? (sqrt(rem) * skk / nrm) : skk);
        }
        __syncthreads();
        double nre = 0.0, nim = 0.0;
        if (tid < NN) {                 // phiB <- phase(E_t) * (S2' @ phiB)
            const int ii = tid;
            double are = 0.0, aim = 0.0;
            for (int jj = 0; jj < NN; ++jj) {
                double sv = (double)S2l[ii][jj];
                are += sv * phre[jj];
                aim += sv * phim[jj];
            }
            double th = (double)EL[cur][ii] * (TWO_PI * ICM2IFS) * dtb;   // |th| < ~0.1
            double x2 = th * th;        // poly sincos, |err| ~1e-16 at this range
            double sph = th * (1.0 + x2 * (-1.0 / 6.0 + x2 * (1.0 / 120.0 + x2 * (-1.0 / 5040.0 + x2 * (1.0 / 362880.0)))));
            double cph = 1.0 + x2 * (-0.5 + x2 * (1.0 / 24.0 + x2 * (-1.0 / 720.0 + x2 * (1.0 / 40320.0))));
            nre = cph * are + sph * aim;            // exp(-iEw) = c - i s
            nim = cph * aim - sph * are;
            redl[ii] = nre * nre + nim * nim;
        }
        __syncthreads();
        if (tid < NN) {                 // normalize, update carry + phi2
            double sum = 0.0;
            for (int jj = 0; jj < NN; ++jj) sum += redl[jj];
            double sc = 1.0 / sqrt(sum);
            nre *= sc; nim *= sc;
            phre[tid] = nre; phim[tid] = nim;
            phi2l[tid] = (float)(nre * nre + nim * nim);
        }
        __syncthreads();
        if ((t % NSI) == 0 && iblk == 0 && tid < NN) {   // ploc = C_t @ phiB
            const int ii = tid;
            double are = 0.0, aim = 0.0;
            for (int jj = 0; jj < NN; ++jj) {
                double cij = (double)CpN[cur][jj][ii];   // C_t[i][j] = CT_t[j][i]
                are += cij * phre[jj];
                aim += cij * phim[jj];
            }
            out[((size_t)b * 61 + t / NSI) * NN + ii] = (float)(are * are + aim * aim);
        }

        // ---- commit prefetched C_{t+1}/E_{t+1}/kk_t into dead ping-pong slots ----
        if (t < NSTEPS) {
            const int e0 = tid * 2;
            CpN[1 - cur][e0 >> 5][e0 & 31] = cpre.x;
            CpN[1 - cur][e0 >> 5][(e0 & 31) + 1] = cpre.y;
            if (tid < NN) EL[1 - cur][tid] = epre;
            else if (tid < 2 * NN) kkL[1 - cur][tid - NN] = kpre;
        }
    }
}

// ---------------------------------------------------------------------------
extern "C" void kernel_launch(void* const* d_in, const int* in_sizes, int n_in,
                              void* d_out, int out_size, void* d_ws, size_t ws_size,
                              hipStream_t stream)
{
    const float* Tarr = (const float*)d_in[0];
    const float* ErA  = (const float*)d_in[1];
    const float* ctA  = (const float*)d_in[2];
    const float* dtA  = (const float*)d_in[4];
    const float* psi0 = (const float*)d_in[6];
    const float* Hf   = (const float*)d_in[7];
    const float* W1   = (const float*)d_in[8];
    const float* b1   = (const float*)d_in[9];
    const float* W2   = (const float*)d_in[10];
    const float* b2   = (const float*)d_in[11];
    const float* W3   = (const float*)d_in[12];
    const float* b3   = (const float*)d_in[13];
    const float* W4   = (const float*)d_in[14];
    const float* b4   = (const float*)d_in[15];

    unsigned int* cnt = (unsigned int*)d_ws;                    // 32*600 counters
    float* E_all  = (float*)(cnt + (size_t)NB * NSTEPS);        // 32*601*32
    float* CT_all = E_all + (size_t)NB * NT1 * NN;              // 32*601*32*32
    float* W2p    = CT_all + (size_t)NB * NT1 * NN * NN;        // 7680
    float* W3p    = W2p + 8 * NKB * 48;                         // 7680
    float4* L1W4  = (float4*)(W3p + 8 * NKB * 48);              // 80 f4
    float4* L1B4  = L1W4 + NU;                                  // 80 f4
    float* bpad   = (float*)(L1B4 + NU);                        // 3*80
    float* S2_g   = bpad + 3 * NU;                              // 2*32*32*32
    int*   kk_all = (int*)(S2_g + 2 * (size_t)NB * NN * NN);    // 32*600*32
    float* outp   = (float*)d_out;

    hipMemsetAsync(cnt, 0, (size_t)NB * NSTEPS * sizeof(unsigned int), stream);
    eigh_kernel<<<NB * NT1, 64, 0, stream>>>(Hf, E_all, CT_all);
    wtrans_kernel<<<1, 256, 0, stream>>>(W1, b1, W2, W3, b2, b3, W4,
                                         W2p, W3p, L1W4, L1B4, bpad);
    kk_kernel<<<NB * NSTEPS, 256, 0, stream>>>(CT_all, kk_all);

    const size_t dynf = (size_t)(2 * 8 * NKB * 48) + 8 * NU + 4 * NU + NU * 128;
    persist_kernel<<<NB * 8, 512, dynf * sizeof(float), stream>>>(E_all, CT_all,
        kk_all, psi0, Tarr, ErA, ctA, dtA, W2p, W3p, L1W4, L1B4, bpad, b4,
        S2_g, cnt, outp);
}

// Round 11
// 20563.399 us; speedup vs baseline: 1.2796x; 1.2796x over previous
//
#include <hip/hip_runtime.h>
#include <math.h>

#define NB 32
#define NN 32
#define NSTEPS 600
#define NT1 601
#define NSI 10
#define NH 75
#define NU 80      // padded u (8 groups x 10)
#define NKB 20     // padded k-blocks of 4 (k padded 75 -> 80)

#define ICM2IFS 2.99792458e-05
#define KBOLTZ 0.6950389f
#define TWO_PI 6.283185307179586476925286766559

__device__ __forceinline__ float elu1(float x) { return x > 0.f ? x : (__expf(x) - 1.f); }

// ---------------------------------------------------------------------------
// Phase A: batched 32x32 symmetric eigensolver (parallel cyclic Jacobi).
// A/rotations FP64; V accumulated FP32 (R10-proven: same absmax, less LDS).
// ---------------------------------------------------------------------------
__global__ __launch_bounds__(64) void eigh_kernel(const float* __restrict__ Hf,
                                                  float* __restrict__ E_all,
                                                  float* __restrict__ CT_all)
{
    __shared__ double A[NN][NN + 1];
    __shared__ float  V[NN][NN + 1];
    __shared__ double csC[16], csS[16];
    __shared__ int   prC[16], qrC[16];
    __shared__ double redv;
    __shared__ int   rankl[NN];

    const int idx = blockIdx.x;      // b*601 + t
    const int tid = threadIdx.x;
    const float* Hp = Hf + (size_t)idx * (NN * NN);

    for (int e = tid; e < NN * NN; e += 64) {
        A[e >> 5][e & 31] = (double)Hp[e];
        V[e >> 5][e & 31] = ((e >> 5) == (e & 31)) ? 1.f : 0.f;
    }
    __syncthreads();

    double part = 0.0;
    for (int e = tid; e < NN * NN; e += 64) { double v = A[e >> 5][e & 31]; part += v * v; }
    #pragma unroll
    for (int off = 32; off > 0; off >>= 1) part += __shfl_down(part, off);
    if (tid == 0) redv = part;
    __syncthreads();
    const double tol2 = 1e-20 * redv;

    for (int sweep = 0; sweep < 10; ++sweep) {
        for (int r = 0; r < NN - 1; ++r) {
            if (tid < 16) {
                int m = tid, p, q;
                if (m == 0) { p = 0; q = 1 + (r % 31); }
                else { p = 1 + ((m + r) % 31); q = 1 + ((31 - m + r) % 31); }
                double apq = A[p][q];
                double c = 1.0, sn = 0.0;
                if (apq != 0.0) {
                    double theta = 0.5 * (A[q][q] - A[p][p]) / apq;
                    double tt = 1.0 / (fabs(theta) + sqrt(theta * theta + 1.0));
                    if (theta < 0.0) tt = -tt;
                    c = 1.0 / sqrt(tt * tt + 1.0);
                    sn = tt * c;
                }
                csC[m] = c; csS[m] = sn; prC[m] = p; qrC[m] = q;
            }
            __syncthreads();
            #pragma unroll
            for (int it = 0; it < 8; ++it) {          // rows: A <- J^T A
                int task = tid + it * 64;
                int m = task >> 5, jc = task & 31;
                int p = prC[m], q = qrC[m];
                double c = csC[m], sn = csS[m];
                double ap = A[p][jc], aq = A[q][jc];
                A[p][jc] = c * ap - sn * aq;
                A[q][jc] = sn * ap + c * aq;
            }
            __syncthreads();
            #pragma unroll
            for (int it = 0; it < 16; ++it) {         // cols: A <- A J (f64), V <- V J (f32)
                int task = tid + it * 64;
                int m = (task >> 5) & 15, ir = task & 31;
                int p = prC[m], q = qrC[m];
                if (task < 512) {
                    double c = csC[m], sn = csS[m];
                    double aip = A[ir][p], aiq = A[ir][q];
                    A[ir][p] = c * aip - sn * aiq;
                    A[ir][q] = sn * aip + c * aiq;
                } else {
                    float cf = (float)csC[m], sf = (float)csS[m];
                    float vip = V[ir][p], viq = V[ir][q];
                    V[ir][p] = cf * vip - sf * viq;
                    V[ir][q] = sf * vip + cf * viq;
                }
            }
            __syncthreads();
        }
        if (sweep >= 3) {
            double o = 0.0;
            for (int e = tid; e < NN * NN; e += 64) {
                int i2 = e >> 5, j2 = e & 31;
                double v = A[i2][j2];
                o += (i2 != j2) ? v * v : 0.0;
            }
            #pragma unroll
            for (int off = 32; off > 0; off >>= 1) o += __shfl_down(o, off);
            if (tid == 0) redv = o;
            __syncthreads();
            if (redv <= tol2) break;
        }
    }
    __syncthreads();

    if (tid < NN) {
        double ei = A[tid][tid];
        int rk = 0;
        for (int j2 = 0; j2 < NN; ++j2) {
            double ej = A[j2][j2];
            rk += (ej < ei || (ej == ei && j2 < tid)) ? 1 : 0;
        }
        rankl[tid] = rk;
        E_all[(size_t)idx * NN + rk] = (float)ei;
    }
    __syncthreads();
    float* ct = CT_all + (size_t)idx * NN * NN;
    for (int e = tid; e < NN * NN; e += 64) {
        int col = e >> 5, m2 = e & 31;
        ct[(size_t)rankl[col] * NN + m2] = V[m2][col];
    }
}

// ---------------------------------------------------------------------------
// Phase A2: kk[b,s,j] = argmax_i S[b,s,i,j]^2 (first index on ties)
// ---------------------------------------------------------------------------
__global__ __launch_bounds__(256) void kk_kernel(const float* __restrict__ CT_all,
                                                 int* __restrict__ kk_all)
{
    __shared__ float Ct[NN][NN + 1], Cp[NN][NN + 1], S[NN][NN + 1];
    const int blk = blockIdx.x;                // b*600 + (s-1)
    const int b = blk / NSTEPS, s = blk % NSTEPS + 1;
    const int tid = threadIdx.x;
    const float* ctg = CT_all + ((size_t)b * NT1 + s) * (NN * NN);
    const float* cpg = CT_all + ((size_t)b * NT1 + s - 1) * (NN * NN);
    for (int e = tid; e < NN * NN; e += 256) {
        Ct[e >> 5][e & 31] = ctg[e];
        Cp[e >> 5][e & 31] = cpg[e];
    }
    __syncthreads();
    for (int e = tid; e < NN * NN; e += 256) {
        int i = e >> 5, j = e & 31;
        float acc = 0.f;
        for (int m = 0; m < NN; ++m) acc += Ct[i][m] * Cp[j][m];
        S[i][j] = acc;
    }
    __syncthreads();
    if (tid < NN) {
        const int j = tid;
        float best = -1.f; int bi = 0;
        for (int i = 0; i < NN; ++i) {
            float v = S[i][j]; v *= v;
            if (v > best) { best = v; bi = i; }
        }
        kk_all[(size_t)blk * NN + j] = bi;
    }
}

// ---------------------------------------------------------------------------
// Pack weights: Wp[ug 8][kb 20][kp 4][12] (10 u + 2 pad, 16B rows; zero pad).
// L1W4/L1B4 float4; bpad = b2[80] | b3[80] | W4[80].
// ---------------------------------------------------------------------------
__global__ void wtrans_kernel(const float* __restrict__ W1, const float* __restrict__ b1,
                              const float* __restrict__ W2, const float* __restrict__ W3,
                              const float* __restrict__ b2, const float* __restrict__ b3,
                              const float* __restrict__ W4,
                              float* __restrict__ W2p, float* __restrict__ W3p,
                              float4* __restrict__ L1W4, float4* __restrict__ L1B4,
                              float* __restrict__ bpad)
{
    const int tid = threadIdx.x;
    const int tot = 8 * NKB * 4 * 12;          // 7680
    for (int e = tid; e < tot; e += 256) {
        int ug = e / (NKB * 4 * 12);
        int kb = (e / (4 * 12)) % NKB;
        int kp = (e / 12) & 3;
        int uu = e % 12;
        int u = ug * 10 + uu;
        int k = kb * 4 + kp;
        float v2 = 0.f, v3 = 0.f;
        if (uu < 10 && u < NH && k < NH) {
            v2 = W2[u * NH + k];
            v3 = W3[u * NH + k];
        }
        W2p[e] = v2; W3p[e] = v3;
    }
    if (tid < NU) {
        if (tid < NH) {
            const float* w = W1 + tid * 8;
            L1W4[tid] = make_float4(w[0], w[1], w[2], w[7]);
            L1B4[tid] = make_float4(w[3], w[4], w[5], b1[tid]);
            bpad[tid]          = b2[tid];
            bpad[NU + tid]     = b3[tid];
            bpad[2 * NU + tid] = W4[tid];
        } else {
            L1W4[tid] = make_float4(0.f, 0.f, 0.f, 0.f);
            L1B4[tid] = make_float4(0.f, 0.f, 0.f, 0.f);
            bpad[tid] = 0.f; bpad[NU + tid] = 0.f; bpad[2 * NU + tid] = 0.f;
        }
    }
}

// ---------------------------------------------------------------------------
// Phase B: ONE persistent kernel, 256 blocks x 512 thr (8 waves, 2/SIMD).
// Thread = (ug = tid>>6, rg = tid&63): tile 10u x 2r — the R9-proven mapping.
// CHANGE vs R9: layer-2/3 weights are read from GLOBAL via provably
// wave-uniform addresses (readfirstlane'd ug) -> scalar s_load path into
// SGPRs, v_fmac with SGPR operand. Weight traffic leaves the LDS pipe
// entirely (R9's 18us/step of broadcast ds_read_b128 -> scalar pipe, sK$/L2
// resident 24 KB). LDS keeps only h float2 reads. Dynamic LDS 73->45 KB.
// Barrier / fp64 prologue / prefetch identical to R9.
// ---------------------------------------------------------------------------
__global__ __launch_bounds__(512, 2) void persist_kernel(
    const float* __restrict__ E_all, const float* __restrict__ CT_all,
    const int* __restrict__ kk_all, const float* __restrict__ psi0,
    const float* __restrict__ Tarr, const float* __restrict__ ErA,
    const float* __restrict__ ctA, const float* __restrict__ dtA,
    const float* __restrict__ W2p, const float* __restrict__ W3p,
    const float4* __restrict__ L1W4g, const float4* __restrict__ L1B4g,
    const float* __restrict__ bpad, const float* __restrict__ b4v,
    float* __restrict__ S2_g, unsigned int* __restrict__ cnt,
    float* __restrict__ out)
{
    extern __shared__ __align__(16) float dyn[];
    float4* L1Wl = (float4*)dyn;                // 80 f4
    float4* L1Bl = L1Wl + NU;                   // 80 f4
    float* cst  = (float*)(L1Bl + NU);          // 80
    float* b2l  = cst + NU;                     // 80
    float* b3l  = b2l + NU;                     // 80
    float* W4l  = b3l + NU;                     // 80
    float* hbuf = W4l + NU;                     // 80*128 = 10240

    __shared__ float CpN[2][NN][NN + 1];
    __shared__ float S2l[NN][NN + 1];
    __shared__ float4 featS[128];               // {DE, ratio, Sv, ex} per row
    __shared__ float2 a4b2[8][64];
    __shared__ float EL[2][NN];
    __shared__ int   kkL[2][NN];
    __shared__ double phre[NN], phim[NN], redl[NN];
    __shared__ float phi2l[NN];

    const int tid  = threadIdx.x;
    const int b    = blockIdx.x & 31;           // siblings: b, 32+b, ..., 224+b
    const int iblk = blockIdx.x >> 5;
    const int i0   = iblk * 4;
    const int ug   = __builtin_amdgcn_readfirstlane(tid >> 6);  // uniform wave id
    const int rg   = tid & 63;                  // 0..63
    const int U    = ug * 10;

    const float kbt = KBOLTZ * Tarr[b];
    const float er  = ErA[b];
    const float cti = ctA[b];
    const double dtb = (double)dtA[b];
    const float b4s = b4v[0];

    // uniform weight panel bases (scalar-load path)
    const float4* W2g = (const float4*)(W2p + (size_t)ug * (NKB * 48));
    const float4* W3g = (const float4*)(W3p + (size_t)ug * (NKB * 48));

    // ---- stage small loop-invariant tables into LDS (once) ----
    if (tid < NU) {
        L1Wl[tid] = L1W4g[tid];
        L1Bl[tid] = L1B4g[tid];
        b2l[tid] = bpad[tid];
        b3l[tid] = bpad[NU + tid];
        W4l[tid] = bpad[2 * NU + tid];
    }
    __syncthreads();
    if (tid < NU) {     // per-b constant part of layer-1 preactivation
        float4 lb = L1Bl[tid];
        cst[tid] = lb.w + lb.x * kbt + lb.y * er + lb.z * cti;
    }

    // ---- prime: C_0, C_1, E[0], E[1], kk[0]; init phiB ----
    {
        const float* c0g = CT_all + (size_t)b * NT1 * NN * NN;
        const float* c1g = c0g + NN * NN;
        for (int e = tid; e < NN * NN; e += 512) {
            CpN[0][e >> 5][e & 31] = c0g[e];
            CpN[1][e >> 5][e & 31] = c1g[e];
        }
        if (tid < NN) {
            EL[0][tid] = E_all[((size_t)b * NT1 + 0) * NN + tid];
            EL[1][tid] = E_all[((size_t)b * NT1 + 1) * NN + tid];
            kkL[1][tid] = kk_all[(size_t)b * NSTEPS * NN + tid];
        }
        __syncthreads();
        if (tid < NN) {
            const int i = tid;
            double acc = 0.0;
            for (int j = 0; j < NN; ++j) acc += (double)CpN[0][i][j] * (double)psi0[b * NN + j];
            phre[i] = acc; phim[i] = 0.0;
            phi2l[i] = (float)(acc * acc);
            if (iblk == 0) {
                float p0 = psi0[b * NN + i];
                out[((size_t)b * 61) * NN + i] = p0 * p0;
            }
        }
    }

    for (int t = 1; t <= NSTEPS; ++t) {
        __syncthreads();
        const int cur = t & 1;

        // ---- features (one thread per row) ----
        if (tid < 128) {
            const int r = tid;
            const int i = i0 + (r >> 5);
            const int j = r & 31;
            float Sv = 0.f;
            for (int m = 0; m < NN; ++m) Sv += CpN[cur][i][m] * CpN[1 - cur][j][m];
            const int kj = kkL[cur][j];
            const float DE = (i == kj) ? 0.f : (EL[cur][i] - EL[1 - cur][j]);
            const float p_i = phi2l[i], p_j = phi2l[j];
            const float ratio = (p_j > 0.01f * p_i) ? (p_i / p_j) : 100.f;
            const float ex = __expf(DE / kbt);
            featS[r] = make_float4(DE, ratio, Sv, ex);
        }
        __syncthreads();

        // ---- issue prefetch loads for step t+1 (retire during MLP) ----
        float2 cpre = make_float2(0.f, 0.f);
        float  epre = 0.f;
        int    kpre = 0;
        if (t < NSTEPS) {
            const float* c1g = CT_all + ((size_t)b * NT1 + t + 1) * (NN * NN);
            cpre = ((const float2*)c1g)[tid];
            if (tid < NN) epre = E_all[((size_t)b * NT1 + t + 1) * NN + tid];
            else if (tid < 2 * NN) kpre = kk_all[((size_t)b * NSTEPS + t) * NN + (tid - NN)];
        }

        // ---- layer 1 (features -> h1), tile 10u x 2r ----
        {
            float4 f0 = featS[2 * rg], f1 = featS[2 * rg + 1];
            #pragma unroll
            for (int u = 0; u < 10; ++u) {
                float4 wv = L1Wl[U + u];
                float c = cst[U + u];
                float2 hv;
                hv.x = elu1(c + wv.x * f0.x + wv.y * f0.y + wv.z * f0.z + wv.w * f0.w);
                hv.y = elu1(c + wv.x * f1.x + wv.y * f1.y + wv.z * f1.z + wv.w * f1.w);
                *(float2*)(hbuf + (U + u) * 128 + 2 * rg) = hv;
            }
        }
        __syncthreads();

        // ---- layer 2 (h1 -> h2): weights via scalar loads from global ----
        float2 acc[10];
        #pragma unroll
        for (int u = 0; u < 10; ++u) { float bb = b2l[U + u]; acc[u] = make_float2(bb, bb); }
        for (int kb = 0; kb < NKB; ++kb) {
            float4 wv[12];
            float2 hv[4];
            #pragma unroll
            for (int m = 0; m < 12; ++m) wv[m] = W2g[kb * 12 + m];   // uniform -> s_load
            #pragma unroll
            for (int kk = 0; kk < 4; ++kk)
                hv[kk] = *(const float2*)(hbuf + (kb * 4 + kk) * 128 + 2 * rg);
            #pragma unroll
            for (int kk = 0; kk < 4; ++kk) {
                const float* wf = (const float*)&wv[kk * 3];
                #pragma unroll
                for (int u = 0; u < 10; ++u) {
                    float wS = wf[u];
                    acc[u].x += wS * hv[kk].x; acc[u].y += wS * hv[kk].y;
                }
            }
        }
        __syncthreads();    // all reads of h1 done before overwriting hbuf
        #pragma unroll
        for (int u = 0; u < 10; ++u) {
            float2 hv; hv.x = elu1(acc[u].x); hv.y = elu1(acc[u].y);
            *(float2*)(hbuf + (U + u) * 128 + 2 * rg) = hv;
        }
        __syncthreads();

        // ---- layer 3 (h2 -> h3 in registers) ----
        #pragma unroll
        for (int u = 0; u < 10; ++u) { float bb = b3l[U + u]; acc[u] = make_float2(bb, bb); }
        for (int kb = 0; kb < NKB; ++kb) {
            float4 wv[12];
            float2 hv[4];
            #pragma unroll
            for (int m = 0; m < 12; ++m) wv[m] = W3g[kb * 12 + m];   // uniform -> s_load
            #pragma unroll
            for (int kk = 0; kk < 4; ++kk)
                hv[kk] = *(const float2*)(hbuf + (kb * 4 + kk) * 128 + 2 * rg);
            #pragma unroll
            for (int kk = 0; kk < 4; ++kk) {
                const float* wf = (const float*)&wv[kk * 3];
                #pragma unroll
                for (int u = 0; u < 10; ++u) {
                    float wS = wf[u];
                    acc[u].x += wS * hv[kk].x; acc[u].y += wS * hv[kk].y;
                }
            }
        }
        // ---- layer 4 partials ----
        {
            float2 p4 = make_float2(0.f, 0.f);
            #pragma unroll
            for (int u = 0; u < 10; ++u) {
                float w4 = W4l[U + u];
                p4.x += w4 * elu1(acc[u].x); p4.y += w4 * elu1(acc[u].y);
            }
            a4b2[ug][rg] = p4;
        }
        __syncthreads();
        if (tid < 128) {
            const int r = tid;
            float a4 = b4s;
            #pragma unroll
            for (int g = 0; g < 8; ++g) {
                float2 pv = a4b2[g][r >> 1];
                a4 += (r & 1) ? pv.y : pv.x;
            }
            const float corr = elu1(a4) + 1.f;
            const float Sv = featS[r].z;
            const int i = i0 + (r >> 5);
            const int j = r & 31;
            S2_g[(((size_t)cur * NB + b) * NN + i) * NN + j] = Sv * corr;
            __threadfence();                    // make S2 agent-visible
        }
        __syncthreads();

        // ---- sibling barrier (8 blocks of this b), per-step counter ----
        if (tid == 0) {
            unsigned int* c = cnt + (size_t)b * NSTEPS + (t - 1);
            __hip_atomic_fetch_add(c, 1u, __ATOMIC_RELEASE, __HIP_MEMORY_SCOPE_AGENT);
            while (__hip_atomic_load(c, __ATOMIC_ACQUIRE, __HIP_MEMORY_SCOPE_AGENT) < 8u)
                __builtin_amdgcn_s_sleep(1);
        }
        __syncthreads();

        // ---- complete step t (replicated per block, fp64) ----
        {
            const float* s2src = S2_g + ((size_t)cur * NB + b) * (NN * NN);
            for (int e = tid; e < NN * NN; e += 512) S2l[e >> 5][e & 31] = s2src[e];
        }
        __syncthreads();
        if (tid < NN) {                 // column correction (kk = kk_all[t-1])
            const int jj = tid;
            const int kj2 = kkL[cur][jj];
            double cd = 0.0;
            for (int i2 = 0; i2 < NN; ++i2) {
                double v = (double)S2l[i2][jj];
                cd += (i2 == kj2) ? 0.0 : v * v;
            }
            double skk = (double)S2l[kj2][jj];
            double nrm = fabs(skk); nrm = (nrm > 0.0) ? nrm : 1.0;
            double rem = 1.0 - cd;
            S2l[kj2][jj] = (float)((rem > 0.0) ? (sqrt(rem) * skk / nrm) : skk);
        }
        __syncthreads();
        double nre = 0.0, nim = 0.0;
        if (tid < NN) {                 // phiB <- phase(E_t) * (S2' @ phiB)
            const int ii = tid;
            double are = 0.0, aim = 0.0;
            for (int jj = 0; jj < NN; ++jj) {
                double sv = (double)S2l[ii][jj];
                are += sv * phre[jj];
                aim += sv * phim[jj];
            }
            double th = (double)EL[cur][ii] * (TWO_PI * ICM2IFS) * dtb;   // |th| < ~0.1
            double x2 = th * th;        // poly sincos, |err| ~1e-16 at this range
            double sph = th * (1.0 + x2 * (-1.0 / 6.0 + x2 * (1.0 / 120.0 + x2 * (-1.0 / 5040.0 + x2 * (1.0 / 362880.0)))));
            double cph = 1.0 + x2 * (-0.5 + x2 * (1.0 / 24.0 + x2 * (-1.0 / 720.0 + x2 * (1.0 / 40320.0))));
            nre = cph * are + sph * aim;            // exp(-iEw) = c - i s
            nim = cph * aim - sph * are;
            redl[ii] = nre * nre + nim * nim;
        }
        __syncthreads();
        if (tid < NN) {                 // normalize, update carry + phi2
            double sum = 0.0;
            for (int jj = 0; jj < NN; ++jj) sum += redl[jj];
            double sc = 1.0 / sqrt(sum);
            nre *= sc; nim *= sc;
            phre[tid] = nre; phim[tid] = nim;
            phi2l[tid] = (float)(nre * nre + nim * nim);
        }
        __syncthreads();
        if ((t % NSI) == 0 && iblk == 0 && tid < NN) {   // ploc = C_t @ phiB
            const int ii = tid;
            double are = 0.0, aim = 0.0;
            for (int jj = 0; jj < NN; ++jj) {
                double cij = (double)CpN[cur][jj][ii];   // C_t[i][j] = CT_t[j][i]
                are += cij * phre[jj];
                aim += cij * phim[jj];
            }
            out[((size_t)b * 61 + t / NSI) * NN + ii] = (float)(are * are + aim * aim);
        }

        // ---- commit prefetched C_{t+1}/E_{t+1}/kk_t into dead ping-pong slots ----
        if (t < NSTEPS) {
            const int e0 = tid * 2;
            CpN[1 - cur][e0 >> 5][e0 & 31] = cpre.x;
            CpN[1 - cur][e0 >> 5][(e0 & 31) + 1] = cpre.y;
            if (tid < NN) EL[1 - cur][tid] = epre;
            else if (tid < 2 * NN) kkL[1 - cur][tid - NN] = kpre;
        }
    }
}

// ---------------------------------------------------------------------------
extern "C" void kernel_launch(void* const* d_in, const int* in_sizes, int n_in,
                              void* d_out, int out_size, void* d_ws, size_t ws_size,
                              hipStream_t stream)
{
    const float* Tarr = (const float*)d_in[0];
    const float* ErA  = (const float*)d_in[1];
    const float* ctA  = (const float*)d_in[2];
    const float* dtA  = (const float*)d_in[4];
    const float* psi0 = (const float*)d_in[6];
    const float* Hf   = (const float*)d_in[7];
    const float* W1   = (const float*)d_in[8];
    const float* b1   = (const float*)d_in[9];
    const float* W2   = (const float*)d_in[10];
    const float* b2   = (const float*)d_in[11];
    const float* W3   = (const float*)d_in[12];
    const float* b3   = (const float*)d_in[13];
    const float* W4   = (const float*)d_in[14];
    const float* b4   = (const float*)d_in[15];

    unsigned int* cnt = (unsigned int*)d_ws;                    // 32*600 counters
    float* E_all  = (float*)(cnt + (size_t)NB * NSTEPS);        // 32*601*32
    float* CT_all = E_all + (size_t)NB * NT1 * NN;              // 32*601*32*32
    float* W2p    = CT_all + (size_t)NB * NT1 * NN * NN;        // 7680
    float* W3p    = W2p + 8 * NKB * 48;                         // 7680
    float4* L1W4  = (float4*)(W3p + 8 * NKB * 48);              // 80 f4
    float4* L1B4  = L1W4 + NU;                                  // 80 f4
    float* bpad   = (float*)(L1B4 + NU);                        // 3*80
    float* S2_g   = bpad + 3 * NU;                              // 2*32*32*32
    int*   kk_all = (int*)(S2_g + 2 * (size_t)NB * NN * NN);    // 32*600*32
    float* outp   = (float*)d_out;

    hipMemsetAsync(cnt, 0, (size_t)NB * NSTEPS * sizeof(unsigned int), stream);
    eigh_kernel<<<NB * NT1, 64, 0, stream>>>(Hf, E_all, CT_all);
    wtrans_kernel<<<1, 256, 0, stream>>>(W1, b1, W2, W3, b2, b3, W4,
                                         W2p, W3p, L1W4, L1B4, bpad);
    kk_kernel<<<NB * NSTEPS, 256, 0, stream>>>(CT_all, kk_all);

    const size_t dynf = (size_t)(8 * NU) + 4 * NU + NU * 128;   // L1 tables + biases + hbuf
    persist_kernel<<<NB * 8, 512, dynf * sizeof(float), stream>>>(E_all, CT_all,
        kk_all, psi0, Tarr, ErA, ctA, dtA, W2p, W3p, L1W4, L1B4, bpad, b4,
        S2_g, cnt, outp);
}